// Round 4
// baseline (752.315 us; speedup 1.0000x reference)
//
#include <hip/hip_runtime.h>

typedef _Float16 HALF;
typedef _Float16 f16x8 __attribute__((ext_vector_type(8)));
typedef float f32x4 __attribute__((ext_vector_type(4)));
typedef int i32x4 __attribute__((ext_vector_type(4)));

// ---- fused weight conversion: fp32 (27*CI, CO) -> fp16 tiled [KP/32][CO_PAD][32], zero padded
struct WArgs { const float* W[8]; HALF* dst[8]; };

__global__ void convert_all_w_kernel(WArgs a)
{
    const int CIs[8]  = {64, 64, 64, 64, 32, 32, 16, 16};
    const int COs[8]  = {64, 64, 64, 32, 32, 16, 16, 3};
    const int COPs[8] = {64, 64, 64, 32, 32, 16, 16, 16};
    const int L = blockIdx.y;
    const int CI = CIs[L], CO = COs[L], COP = COPs[L];
    const int K = 27 * CI, KP = (K + 31) & ~31;
    const int total = COP * KP;
    for (int i = blockIdx.x * 256 + threadIdx.x; i < total; i += gridDim.x * 256) {
        int jp = i / KP;          // out channel (padded)
        int kp = i - jp * KP;     // k (padded)
        float v = (jp < CO && kp < K) ? a.W[L][(size_t)kp * CO + jp] : 0.f;
        a.dst[L][((size_t)(kp >> 5) * COP + jp) * 32 + (kp & 31)] = (HALF)v;
    }
}

__global__ void convert_x_kernel(const float* __restrict__ x, HALF* __restrict__ xh, int total)
{
    int i = blockIdx.x * 256 + threadIdx.x;
    if (i < total) xh[i] = (HALF)x[i];
}

// ---- conv: barrier-free, branch-free main loop; compiler-scheduled (rounds 0-3
// proved source pipelining / asm vmcnt both fail to beat it). Latency-bound at
// ~32MB traffic -> lever is occupancy x per-wave MLP: NMT=1 doubles the grid
// (5.9 blocks/CU) while launch_bounds(256,2) keeps the allocator from squeezing
// registers (round 1's VGPR=40 collapse came from bounds=6, not NMT=1).
// FUSED: apply producer's batchnorm+relu on the fly during the gather.
// XCD-swizzled blockIdx: contiguous row ranges share an XCD L2 (table > 4MiB/XCD).
template<int CI, int CO_PAD, int NMT, bool FUSED>
__global__ __launch_bounds__(256, 2) void conv_kernel(
    const HALF* __restrict__ h, const int* __restrict__ nbr,
    const HALF* __restrict__ Wt, HALF* __restrict__ yout,
    float* __restrict__ sums, int n,
    const float* __restrict__ psums, const float* __restrict__ pg,
    const float* __restrict__ pb, float pinvn)
{
    constexpr int K    = 27 * CI;
    constexpr int KP   = (K + 31) & ~31;
    constexpr int NCH  = KP / 32;
    constexpr int NJB  = CO_PAD / 16;
    constexpr int NW   = 4;
    constexpr int NCB  = (CI >= 64) ? 2 : 1;
    constexpr int LOG2CI = (CI == 64) ? 6 : ((CI == 32) ? 5 : 4);

    __shared__ float red[2][NW][CO_PAD];

    const int wv   = threadIdx.x >> 6;
    const int lane = threadIdx.x & 63;
    const int l15  = lane & 15;
    const int lq   = lane >> 4;

    // bijective XCD swizzle (8 XCDs): contiguous block chunks land on one XCD
    int bid = blockIdx.x;
    {
        const int nwg = gridDim.x;
        const int q = nwg >> 3, r = nwg & 7;
        const int xcd = bid & 7, idx = bid >> 3;
        bid = (xcd < r ? xcd * (q + 1) : r * (q + 1) + (xcd - r) * q) + idx;
    }
    const int waveRow = bid * (NW * 16 * NMT) + wv * (16 * NMT);

    f32x4 acc[NMT][NJB];
#pragma unroll
    for (int mt = 0; mt < NMT; ++mt)
#pragma unroll
        for (int jb = 0; jb < NJB; ++jb)
#pragma unroll
            for (int r = 0; r < 4; ++r) acc[mt][jb][r] = 0.f;

    // per-lane nbr row offsets (int, not pointers -> fewer VGPRs)
    int  nbo[NMT];
    bool rok[NMT];
#pragma unroll
    for (int mt = 0; mt < NMT; ++mt) {
        const int row = waveRow + mt * 16 + l15;
        rok[mt] = row < n;
        nbo[mt] = min(row, n - 1) * 27;
    }

    // per-lane normalization constants for the channel slots this lane gathers
    f16x8 sc8[NCB], bi8[NCB];
    if constexpr (FUSED) {
#pragma unroll
        for (int cb = 0; cb < NCB; ++cb) {
            const int c0 = cb * 32 + ((lq * 8) & (CI - 1));
#pragma unroll
            for (int j = 0; j < 8; ++j) {
                const int c = c0 + j;
                const float mu  = psums[c] * pinvn;
                const float var = psums[CI + c] * pinvn - mu * mu;
                const float sc  = rsqrtf(var + 1e-3f) * pg[c];
                sc8[cb][j] = (HALF)sc;
                bi8[cb][j] = (HALF)(pb[c] - mu * sc);
            }
        }
    }

    // tap index for a given kc (lq-dependent only for CI==16)
    #define TAPOF(kc) ((CI == 16) ? (2 * (kc) + (lq >> 1)) : ((CI == 64) ? ((kc) >> 1) : (kc)))
    #define CHOF(kc)  (((kc) * 32 + lq * 8) & (CI - 1))

    // ---- 2-deep rolling pipeline (compiler may reschedule; it matches its natural depth)
    int   ipf[2][NMT];
    f16x8 apf[2][NMT];
#pragma unroll
    for (int p = 0; p < 2; ++p) {
#pragma unroll
        for (int mt = 0; mt < NMT; ++mt) {
            const int t   = TAPOF(p);
            const int v   = nbr[nbo[mt] + (t < 27 ? t : 26)];
            const int idx = (rok[mt] && t < 27) ? v : -1;
            ipf[p][mt] = idx;
            apf[p][mt] = *(const f16x8*)(h + ((max(idx, 0) << LOG2CI) + CHOF(p)));
        }
    }

#pragma unroll
    for (int kc = 0; kc < NCH; ++kc) {
        const int cur = kc & 1;                          // compile-time (full unroll)
        const int ccb = (NCB == 2) ? (kc & 1) : 0;

        // B fragments: coalesced from tiled Wt (L2-resident)
        const HALF* wb = Wt + (size_t)kc * (CO_PAD * 32) + lq * 8;
        f16x8 b[NJB];
#pragma unroll
        for (int jb = 0; jb < NJB; ++jb)
            b[jb] = *(const f16x8*)(wb + (size_t)(jb * 16 + l15) * 32);

        // take current stage
        f16x8 a_use[NMT];
        int   i_use[NMT];
#pragma unroll
        for (int mt = 0; mt < NMT; ++mt) { a_use[mt] = apf[cur][mt]; i_use[mt] = ipf[cur][mt]; }

        // refill stage with kc+2
        if (kc + 2 < NCH) {
#pragma unroll
            for (int mt = 0; mt < NMT; ++mt) {
                const int t   = TAPOF(kc + 2);
                const int v   = nbr[nbo[mt] + (t < 27 ? t : 26)];
                const int idx = (rok[mt] && t < 27) ? v : -1;
                ipf[cur][mt] = idx;
                apf[cur][mt] = *(const f16x8*)(h + ((max(idx, 0) << LOG2CI) + CHOF(kc + 2)));
            }
        }

        // consume
#pragma unroll
        for (int mt = 0; mt < NMT; ++mt) {
            f16x8 a = a_use[mt];
            if constexpr (FUSED) {
                a = a * sc8[ccb] + bi8[ccb];             // v_pk_fma_f16
#pragma unroll
                for (int j = 0; j < 8; ++j)
                    a[j] = (a[j] < (HALF)0.f) ? (HALF)0.f : a[j];
            }
            // zero invalid lanes AFTER bn so invalid -> exact 0
            const int m = ~(i_use[mt] >> 31);
            i32x4 ai = __builtin_bit_cast(i32x4, a);
            ai.x &= m; ai.y &= m; ai.z &= m; ai.w &= m;
            a = __builtin_bit_cast(f16x8, ai);
#pragma unroll
            for (int jb = 0; jb < NJB; ++jb)
                acc[mt][jb] = __builtin_amdgcn_mfma_f32_16x16x32_f16(a, b[jb], acc[mt][jb], 0, 0, 0);
        }
    }
    #undef TAPOF
    #undef CHOF

    // ---- epilogue: store RAW pre-norm y (fp16) + per-channel sum/sumsq
    // C/D layout: col = lane&15, row = (lane>>4)*4 + reg
#pragma unroll
    for (int jb = 0; jb < NJB; ++jb) {
        const int col = jb * 16 + l15;
        float s = 0.f, sq = 0.f;
#pragma unroll
        for (int mt = 0; mt < NMT; ++mt) {
            const int rb = waveRow + mt * 16 + lq * 4;
#pragma unroll
            for (int r = 0; r < 4; ++r) {
                if (rb + r < n) {
                    const float v = acc[mt][jb][r];
                    yout[(size_t)(rb + r) * CO_PAD + col] = (HALF)v;
                    s += v;
                    sq += v * v;
                }
            }
        }
        s  += __shfl_xor(s, 16);  s  += __shfl_xor(s, 32);
        sq += __shfl_xor(sq, 16); sq += __shfl_xor(sq, 32);
        if (lane < 16) { red[0][wv][col] = s; red[1][wv][col] = sq; }
    }
    __syncthreads();
    if (threadIdx.x < CO_PAD) {
        float s = 0.f, sq = 0.f;
#pragma unroll
        for (int w = 0; w < NW; ++w) { s += red[0][w][threadIdx.x]; sq += red[1][w][threadIdx.x]; }
        atomicAdd(&sums[threadIdx.x], s);
        atomicAdd(&sums[CO_PAD + threadIdx.x], sq);
    }
}

// ---- final: normalize (no relu), co=3 out of CO_PAD=16, fp32 output
__global__ void bn_out_kernel(const HALF* __restrict__ y, const float* __restrict__ sums,
                              const float* __restrict__ g, const float* __restrict__ b,
                              int n, float invn, float* __restrict__ out)
{
    int i = blockIdx.x * 256 + threadIdx.x;
    if (i >= n * 3) return;
    int row = i / 3;
    int c = i - row * 3;
    float mu  = sums[c] * invn;
    float var = sums[16 + c] * invn - mu * mu;
    float sc  = rsqrtf(var + 1e-3f) * g[c];
    out[i] = ((float)y[(size_t)row * 16 + c] - mu) * sc + b[c];
}

extern "C" void kernel_launch(void* const* d_in, const int* in_sizes, int n_in,
                              void* d_out, int out_size, void* d_ws, size_t ws_size,
                              hipStream_t stream)
{
    const int* nbr4  = (const int*)d_in[0];
    const int* inv43 = (const int*)d_in[1];
    const int* nbr3  = (const int*)d_in[2];
    const int* inv32 = (const int*)d_in[3];
    const int* nbr2  = (const int*)d_in[4];
    const int* inv21 = (const int*)d_in[5];
    const int* nbr1  = (const int*)d_in[6];
    const float* x   = (const float*)d_in[7];

    const int n4 = in_sizes[0] / 27;
    const int n3 = in_sizes[1] / 27;
    const int n2 = in_sizes[3] / 27;
    const int n1 = in_sizes[5] / 27;

    // specs: m4,i4,m3,i3,m2,i2,m1,c5
    const int CIs[8]  = {64, 64, 64, 64, 32, 32, 16, 16};
    const int COPs[8] = {64, 64, 64, 32, 32, 16, 16, 16};
    int KPs[8], wtoff[8];
    int wtot = 0;
    for (int s = 0; s < 8; ++s) {
        KPs[s] = ((27 * CIs[s] + 31) / 32) * 32;
        wtoff[s] = wtot;
        wtot += COPs[s] * KPs[s];
    }

    char* ws = (char*)d_ws;
    HALF* wt = (HALF*)ws;
    size_t off = ((size_t)wtot * sizeof(HALF) + 255) & ~(size_t)255;
    float* sums = (float*)(ws + off);
    off += 8 * 128 * sizeof(float);
    off = (off + 255) & ~(size_t)255;
    HALF* xh = (HALF*)(ws + off);
    off += ((size_t)n4 * 64 * sizeof(HALF) + 255) & ~(size_t)255;
    size_t bufElems = 0;
    {
        size_t cand[4] = {(size_t)n4 * 64, (size_t)n3 * 64, (size_t)n2 * 32, (size_t)n1 * 16};
        for (int i = 0; i < 4; ++i) if (cand[i] > bufElems) bufElems = cand[i];
    }
    HALF* Y0 = (HALF*)(ws + off);
    off += (bufElems * sizeof(HALF) + 255) & ~(size_t)255;
    HALF* Y1 = (HALF*)(ws + off);

    hipMemsetAsync(sums, 0, 8 * 128 * sizeof(float), stream);

    WArgs wa;
    for (int s = 0; s < 8; ++s) { wa.W[s] = (const float*)d_in[8 + 3 * s]; wa.dst[s] = wt + wtoff[s]; }
    {
        int maxTotal = 64 * KPs[0];
        dim3 grid((maxTotal + 255) / 256, 8);
        convert_all_w_kernel<<<grid, 256, 0, stream>>>(wa);
    }
    convert_x_kernel<<<(n4 * 64 + 255) / 256, 256, 0, stream>>>(x, xh, n4 * 64);

#define G(s) ((const float*)d_in[9 + 3 * (s)])
#define B(s) ((const float*)d_in[10 + 3 * (s)])
#define SUMS(s) (sums + (s) * 128)
#define GRID(nn) (((nn) + 63) / 64)

    // m4: xh(n4,64) -> Y0 (raw)
    conv_kernel<64, 64, 1, false><<<GRID(n4), 256, 0, stream>>>(
        xh, nbr4, wt + wtoff[0], Y0, SUMS(0), n4, nullptr, nullptr, nullptr, 0.f);
    // i4: norm(m4) fused; Y0(n4) -> Y1(n3)
    conv_kernel<64, 64, 1, true><<<GRID(n3), 256, 0, stream>>>(
        Y0, inv43, wt + wtoff[1], Y1, SUMS(1), n3, SUMS(0), G(0), B(0), 1.f / n4);
    // m3: norm(i4) fused; Y1 -> Y0
    conv_kernel<64, 64, 1, true><<<GRID(n3), 256, 0, stream>>>(
        Y1, nbr3, wt + wtoff[2], Y0, SUMS(2), n3, SUMS(1), G(1), B(1), 1.f / n3);
    // i3: norm(m3) fused; Y0(n3) -> Y1(n2), co 32
    conv_kernel<64, 32, 1, true><<<GRID(n2), 256, 0, stream>>>(
        Y0, inv32, wt + wtoff[3], Y1, SUMS(3), n2, SUMS(2), G(2), B(2), 1.f / n3);
    // m2: norm(i3) fused; Y1 -> Y0
    conv_kernel<32, 32, 1, true><<<GRID(n2), 256, 0, stream>>>(
        Y1, nbr2, wt + wtoff[4], Y0, SUMS(4), n2, SUMS(3), G(3), B(3), 1.f / n2);
    // i2: norm(m2) fused; Y0(n2) -> Y1(n1), co 16
    conv_kernel<32, 16, 1, true><<<GRID(n1), 256, 0, stream>>>(
        Y0, inv21, wt + wtoff[5], Y1, SUMS(5), n1, SUMS(4), G(4), B(4), 1.f / n2);
    // m1: norm(i2) fused; Y1 -> Y0
    conv_kernel<16, 16, 1, true><<<GRID(n1), 256, 0, stream>>>(
        Y1, nbr1, wt + wtoff[6], Y0, SUMS(6), n1, SUMS(5), G(5), B(5), 1.f / n1);
    // c5: norm(m1) fused; Y0 -> Y1 (raw), then fp32 out
    conv_kernel<16, 16, 1, true><<<GRID(n1), 256, 0, stream>>>(
        Y0, nbr1, wt + wtoff[7], Y1, SUMS(7), n1, SUMS(6), G(6), B(6), 1.f / n1);
    bn_out_kernel<<<(n1 * 3 + 255) / 256, 256, 0, stream>>>(
        Y1, SUMS(7), G(7), B(7), n1, 1.f / n1, (float*)d_out);

#undef G
#undef B
#undef SUMS
#undef GRID
}

// Round 5
// 642.026 us; speedup vs baseline: 1.1718x; 1.1718x over previous
//
#include <hip/hip_runtime.h>

typedef _Float16 HALF;
typedef _Float16 f16x8 __attribute__((ext_vector_type(8)));
typedef float f32x4 __attribute__((ext_vector_type(4)));
typedef int i32x4 __attribute__((ext_vector_type(4)));

// ---- fused weight conversion: fp32 (27*CI, CO) -> fp16 tiled [KP/32][CO_PAD][32], zero padded
struct WArgs { const float* W[8]; HALF* dst[8]; };

__global__ void convert_all_w_kernel(WArgs a)
{
    const int CIs[8]  = {64, 64, 64, 64, 32, 32, 16, 16};
    const int COs[8]  = {64, 64, 64, 32, 32, 16, 16, 3};
    const int COPs[8] = {64, 64, 64, 32, 32, 16, 16, 16};
    const int L = blockIdx.y;
    const int CI = CIs[L], CO = COs[L], COP = COPs[L];
    const int K = 27 * CI, KP = (K + 31) & ~31;
    const int total = COP * KP;
    for (int i = blockIdx.x * 256 + threadIdx.x; i < total; i += gridDim.x * 256) {
        int jp = i / KP;          // out channel (padded)
        int kp = i - jp * KP;     // k (padded)
        float v = (jp < CO && kp < K) ? a.W[L][(size_t)kp * CO + jp] : 0.f;
        a.dst[L][((size_t)(kp >> 5) * COP + jp) * 32 + (kp & 31)] = (HALF)v;
    }
}

__global__ void convert_x_kernel(const float* __restrict__ x, HALF* __restrict__ xh, int total)
{
    int i = blockIdx.x * 256 + threadIdx.x;
    if (i < total) xh[i] = (HALF)x[i];
}

// ---- conv: k-split across waves. Rounds 0-4 established: the NMT=2 per-wave body
// (VGPR~56, compiler 2-deep pipelining) is the best per-wave code, but the grid
// (n/128) caps residency at ~3 waves/SIMD -> latency-bound at 77us/64ch-layer.
// Fix: all 4 waves of a block share the SAME 32 rows; each wave processes 1/4 of
// the kc (tap x channel-half) steps; partial acc tree-reduced via LDS (16KB).
// Grid = n/32 (~12 blocks/CU), per-wave body unchanged -> occupancy x ILP both high.
// sums striped 8-way by block to keep atomic chains short.
// FUSED: apply producer's batchnorm+relu on the fly during the gather.
// XCD-swizzled blockIdx: contiguous row ranges share an XCD L2.
template<int CI, int CO_PAD, int NMT, bool FUSED>
__global__ __launch_bounds__(256, 2) void conv_kernel(
    const HALF* __restrict__ h, const int* __restrict__ nbr,
    const HALF* __restrict__ Wt, HALF* __restrict__ yout,
    float* __restrict__ sums, int n,
    const float* __restrict__ psums, const float* __restrict__ pg,
    const float* __restrict__ pb, float pinvn)
{
    constexpr int K    = 27 * CI;
    constexpr int KP   = (K + 31) & ~31;
    constexpr int NCH  = KP / 32;
    constexpr int NJB  = CO_PAD / 16;
    constexpr int NW   = 4;
    constexpr int CHK  = (NCH + NW - 1) / NW;     // kc steps per wave: 14 / 7 / 4
    constexpr int NCB  = (CI >= 64) ? 2 : 1;
    static_assert(NCB == 1 || (CHK & 1) == 0, "sc8 parity must stay compile-time");
    constexpr int LOG2CI = (CI == 64) ? 6 : ((CI == 32) ? 5 : 4);
    constexpr int ROWS  = 16 * NMT;               // 32 rows per block
    constexpr int PAIRS = NMT * NJB;

    __shared__ f32x4 lred[2][PAIRS * 64];         // 16KB for CI=64/CO=64

    const int wv   = threadIdx.x >> 6;
    const int lane = threadIdx.x & 63;
    const int l15  = lane & 15;
    const int lq   = lane >> 4;

    // bijective XCD swizzle (8 XCDs): contiguous block chunks land on one XCD
    int bid = blockIdx.x;
    {
        const int nwg = gridDim.x;
        const int q = nwg >> 3, r = nwg & 7;
        const int xcd = bid & 7, idx = bid >> 3;
        bid = (xcd < r ? xcd * (q + 1) : r * (q + 1) + (xcd - r) * q) + idx;
    }
    const int rowBase = bid * ROWS;               // same rows for all 4 waves

    f32x4 acc[NMT][NJB];
#pragma unroll
    for (int mt = 0; mt < NMT; ++mt)
#pragma unroll
        for (int jb = 0; jb < NJB; ++jb)
#pragma unroll
            for (int r = 0; r < 4; ++r) acc[mt][jb][r] = 0.f;

    int  nbo[NMT];
    bool rok[NMT];
#pragma unroll
    for (int mt = 0; mt < NMT; ++mt) {
        const int row = rowBase + mt * 16 + l15;
        rok[mt] = row < n;
        nbo[mt] = min(row, n - 1) * 27;
    }

    // per-lane normalization constants (producer bn), striped psums summed over 8 slots
    f16x8 sc8[NCB], bi8[NCB];
    if constexpr (FUSED) {
#pragma unroll
        for (int cb = 0; cb < NCB; ++cb) {
            const int c0 = cb * 32 + ((lq * 8) & (CI - 1));
#pragma unroll
            for (int j = 0; j < 8; ++j) {
                const int c = c0 + j;
                float ssum = 0.f, qsum = 0.f;
#pragma unroll
                for (int k2 = 0; k2 < 8; ++k2) {
                    ssum += psums[k2 * 128 + c];
                    qsum += psums[k2 * 128 + CI + c];
                }
                const float mu  = ssum * pinvn;
                const float var = qsum * pinvn - mu * mu;
                const float sc  = rsqrtf(var + 1e-3f) * pg[c];
                sc8[cb][j] = (HALF)sc;
                bi8[cb][j] = (HALF)(pb[c] - mu * sc);
            }
        }
    }

    #define TAPOF(kc_) ((CI == 16) ? (2 * (kc_) + (lq >> 1)) : ((CI == 64) ? ((kc_) >> 1) : (kc_)))
    #define CHOF(kc_)  ((((kc_) * 32) + lq * 8) & (CI - 1))

    const int kc0 = wv * CHK;                     // this wave's kc range

    // ---- 2-deep rolling pipeline over this wave's chunk (same body as the 77us kernel)
    int   ipf[2][NMT];
    f16x8 apf[2][NMT];
#pragma unroll
    for (int p = 0; p < 2; ++p) {
        const int kc = kc0 + p;                   // always < NCH (max kc0+1 < NCH for all CI)
#pragma unroll
        for (int mt = 0; mt < NMT; ++mt) {
            const int t   = TAPOF(kc);
            const int v   = nbr[nbo[mt] + (t < 27 ? t : 26)];
            const int idx = (rok[mt] && t < 27) ? v : -1;
            ipf[p][mt] = idx;
            apf[p][mt] = *(const f16x8*)(h + ((max(idx, 0) << LOG2CI) + CHOF(kc)));
        }
    }

#pragma unroll
    for (int kc2 = 0; kc2 < CHK; ++kc2) {
        const int kc = kc0 + kc2;
        if (kc >= NCH) break;                     // wave-uniform tail guard
        const int cur = kc2 & 1;                  // compile-time (kc0 even when it matters)
        const int ccb = (NCB == 2) ? (kc2 & 1) : 0;

        // B fragments for this wave's kc (L1/L2-resident tiled Wt)
        const HALF* wb = Wt + (size_t)kc * (CO_PAD * 32) + lq * 8;
        f16x8 b[NJB];
#pragma unroll
        for (int jb = 0; jb < NJB; ++jb)
            b[jb] = *(const f16x8*)(wb + (size_t)(jb * 16 + l15) * 32);

        // take current stage
        f16x8 a_use[NMT];
        int   i_use[NMT];
#pragma unroll
        for (int mt = 0; mt < NMT; ++mt) { a_use[mt] = apf[cur][mt]; i_use[mt] = ipf[cur][mt]; }

        // refill stage with kc+2
        if (kc2 + 2 < CHK && kc + 2 < NCH) {
#pragma unroll
            for (int mt = 0; mt < NMT; ++mt) {
                const int t   = TAPOF(kc + 2);
                const int v   = nbr[nbo[mt] + (t < 27 ? t : 26)];
                const int idx = (rok[mt] && t < 27) ? v : -1;
                ipf[cur][mt] = idx;
                apf[cur][mt] = *(const f16x8*)(h + ((max(idx, 0) << LOG2CI) + CHOF(kc + 2)));
            }
        }

        // consume
#pragma unroll
        for (int mt = 0; mt < NMT; ++mt) {
            f16x8 a = a_use[mt];
            if constexpr (FUSED) {
                a = a * sc8[ccb] + bi8[ccb];      // v_pk_fma_f16
#pragma unroll
                for (int j = 0; j < 8; ++j)
                    a[j] = (a[j] < (HALF)0.f) ? (HALF)0.f : a[j];
            }
            // zero invalid lanes AFTER bn so invalid -> exact 0
            const int m = ~(i_use[mt] >> 31);
            i32x4 ai = __builtin_bit_cast(i32x4, a);
            ai.x &= m; ai.y &= m; ai.z &= m; ai.w &= m;
            a = __builtin_bit_cast(f16x8, ai);
#pragma unroll
            for (int jb = 0; jb < NJB; ++jb)
                acc[mt][jb] = __builtin_amdgcn_mfma_f32_16x16x32_f16(a, b[jb], acc[mt][jb], 0, 0, 0);
        }
    }
    #undef TAPOF
    #undef CHOF

    // ---- cross-wave tree reduction of partial accumulators (3 syncs, 16KB high-water)
    if (wv & 1) {                                 // w1 -> region0, w3 -> region1
#pragma unroll
        for (int mt = 0; mt < NMT; ++mt)
#pragma unroll
            for (int jb = 0; jb < NJB; ++jb)
                lred[wv >> 1][(mt * NJB + jb) * 64 + lane] = acc[mt][jb];
    }
    __syncthreads();
    if (!(wv & 1)) {                              // w0 += region0, w2 += region1
#pragma unroll
        for (int mt = 0; mt < NMT; ++mt)
#pragma unroll
            for (int jb = 0; jb < NJB; ++jb)
                acc[mt][jb] += lred[wv >> 1][(mt * NJB + jb) * 64 + lane];
    }
    __syncthreads();                              // region0 reads done before rewrite
    if (wv == 2) {
#pragma unroll
        for (int mt = 0; mt < NMT; ++mt)
#pragma unroll
            for (int jb = 0; jb < NJB; ++jb)
                lred[0][(mt * NJB + jb) * 64 + lane] = acc[mt][jb];
    }
    __syncthreads();

    if (wv == 0) {
#pragma unroll
        for (int mt = 0; mt < NMT; ++mt)
#pragma unroll
            for (int jb = 0; jb < NJB; ++jb)
                acc[mt][jb] += lred[0][(mt * NJB + jb) * 64 + lane];

        // epilogue: store RAW pre-norm y (fp16) + per-channel sum/sumsq (8-way striped)
        float* sl = sums + (bid & 7) * 128;
#pragma unroll
        for (int jb = 0; jb < NJB; ++jb) {
            const int col = jb * 16 + l15;
            float s = 0.f, sq = 0.f;
#pragma unroll
            for (int mt = 0; mt < NMT; ++mt) {
                const int rb = rowBase + mt * 16 + lq * 4;
#pragma unroll
                for (int r = 0; r < 4; ++r) {
                    if (rb + r < n) {
                        const float v = acc[mt][jb][r];
                        yout[(size_t)(rb + r) * CO_PAD + col] = (HALF)v;
                        s += v;
                        sq += v * v;
                    }
                }
            }
            s  += __shfl_xor(s, 16);  s  += __shfl_xor(s, 32);
            sq += __shfl_xor(sq, 16); sq += __shfl_xor(sq, 32);
            if (lane < 16) {
                atomicAdd(&sl[col], s);
                atomicAdd(&sl[CO_PAD + col], sq);
            }
        }
    }
}

// ---- final: normalize (no relu), co=3 out of CO_PAD=16, fp32 output; striped sums
__global__ void bn_out_kernel(const HALF* __restrict__ y, const float* __restrict__ sums,
                              const float* __restrict__ g, const float* __restrict__ b,
                              int n, float invn, float* __restrict__ out)
{
    int i = blockIdx.x * 256 + threadIdx.x;
    if (i >= n * 3) return;
    int row = i / 3;
    int c = i - row * 3;
    float ssum = 0.f, qsum = 0.f;
#pragma unroll
    for (int k2 = 0; k2 < 8; ++k2) {
        ssum += sums[k2 * 128 + c];
        qsum += sums[k2 * 128 + 16 + c];
    }
    float mu  = ssum * invn;
    float var = qsum * invn - mu * mu;
    float sc  = rsqrtf(var + 1e-3f) * g[c];
    out[i] = ((float)y[(size_t)row * 16 + c] - mu) * sc + b[c];
}

extern "C" void kernel_launch(void* const* d_in, const int* in_sizes, int n_in,
                              void* d_out, int out_size, void* d_ws, size_t ws_size,
                              hipStream_t stream)
{
    const int* nbr4  = (const int*)d_in[0];
    const int* inv43 = (const int*)d_in[1];
    const int* nbr3  = (const int*)d_in[2];
    const int* inv32 = (const int*)d_in[3];
    const int* nbr2  = (const int*)d_in[4];
    const int* inv21 = (const int*)d_in[5];
    const int* nbr1  = (const int*)d_in[6];
    const float* x   = (const float*)d_in[7];

    const int n4 = in_sizes[0] / 27;
    const int n3 = in_sizes[1] / 27;
    const int n2 = in_sizes[3] / 27;
    const int n1 = in_sizes[5] / 27;

    // specs: m4,i4,m3,i3,m2,i2,m1,c5
    const int CIs[8]  = {64, 64, 64, 64, 32, 32, 16, 16};
    const int COPs[8] = {64, 64, 64, 32, 32, 16, 16, 16};
    int KPs[8], wtoff[8];
    int wtot = 0;
    for (int s = 0; s < 8; ++s) {
        KPs[s] = ((27 * CIs[s] + 31) / 32) * 32;
        wtoff[s] = wtot;
        wtot += COPs[s] * KPs[s];
    }

    char* ws = (char*)d_ws;
    HALF* wt = (HALF*)ws;
    size_t off = ((size_t)wtot * sizeof(HALF) + 255) & ~(size_t)255;
    float* sums = (float*)(ws + off);
    off += 8 * 1024 * sizeof(float);              // 8 layers x 8 slots x 128 floats
    off = (off + 255) & ~(size_t)255;
    HALF* xh = (HALF*)(ws + off);
    off += ((size_t)n4 * 64 * sizeof(HALF) + 255) & ~(size_t)255;
    size_t bufElems = 0;
    {
        size_t cand[4] = {(size_t)n4 * 64, (size_t)n3 * 64, (size_t)n2 * 32, (size_t)n1 * 16};
        for (int i = 0; i < 4; ++i) if (cand[i] > bufElems) bufElems = cand[i];
    }
    HALF* Y0 = (HALF*)(ws + off);
    off += (bufElems * sizeof(HALF) + 255) & ~(size_t)255;
    HALF* Y1 = (HALF*)(ws + off);

    hipMemsetAsync(sums, 0, 8 * 1024 * sizeof(float), stream);

    WArgs wa;
    for (int s = 0; s < 8; ++s) { wa.W[s] = (const float*)d_in[8 + 3 * s]; wa.dst[s] = wt + wtoff[s]; }
    {
        int maxTotal = 64 * KPs[0];
        dim3 grid((maxTotal + 255) / 256, 8);
        convert_all_w_kernel<<<grid, 256, 0, stream>>>(wa);
    }
    convert_x_kernel<<<(n4 * 64 + 255) / 256, 256, 0, stream>>>(x, xh, n4 * 64);

#define G(s) ((const float*)d_in[9 + 3 * (s)])
#define B(s) ((const float*)d_in[10 + 3 * (s)])
#define SUMS(s) (sums + (s) * 1024)
#define GRID(nn) (((nn) + 31) / 32)

    // m4: xh(n4,64) -> Y0 (raw)
    conv_kernel<64, 64, 2, false><<<GRID(n4), 256, 0, stream>>>(
        xh, nbr4, wt + wtoff[0], Y0, SUMS(0), n4, nullptr, nullptr, nullptr, 0.f);
    // i4: norm(m4) fused; Y0(n4) -> Y1(n3)
    conv_kernel<64, 64, 2, true><<<GRID(n3), 256, 0, stream>>>(
        Y0, inv43, wt + wtoff[1], Y1, SUMS(1), n3, SUMS(0), G(0), B(0), 1.f / n4);
    // m3: norm(i4) fused; Y1 -> Y0
    conv_kernel<64, 64, 2, true><<<GRID(n3), 256, 0, stream>>>(
        Y1, nbr3, wt + wtoff[2], Y0, SUMS(2), n3, SUMS(1), G(1), B(1), 1.f / n3);
    // i3: norm(m3) fused; Y0(n3) -> Y1(n2), co 32
    conv_kernel<64, 32, 2, true><<<GRID(n2), 256, 0, stream>>>(
        Y0, inv32, wt + wtoff[3], Y1, SUMS(3), n2, SUMS(2), G(2), B(2), 1.f / n3);
    // m2: norm(i3) fused; Y1 -> Y0
    conv_kernel<32, 32, 2, true><<<GRID(n2), 256, 0, stream>>>(
        Y1, nbr2, wt + wtoff[4], Y0, SUMS(4), n2, SUMS(3), G(3), B(3), 1.f / n2);
    // i2: norm(m2) fused; Y0(n2) -> Y1(n1), co 16
    conv_kernel<32, 16, 2, true><<<GRID(n1), 256, 0, stream>>>(
        Y0, inv21, wt + wtoff[5], Y1, SUMS(5), n1, SUMS(4), G(4), B(4), 1.f / n2);
    // m1: norm(i2) fused; Y1 -> Y0
    conv_kernel<16, 16, 2, true><<<GRID(n1), 256, 0, stream>>>(
        Y1, nbr1, wt + wtoff[6], Y0, SUMS(6), n1, SUMS(5), G(5), B(5), 1.f / n1);
    // c5: norm(m1) fused; Y0 -> Y1 (raw), then fp32 out
    conv_kernel<16, 16, 2, true><<<GRID(n1), 256, 0, stream>>>(
        Y0, nbr1, wt + wtoff[7], Y1, SUMS(7), n1, SUMS(6), G(6), B(6), 1.f / n1);
    bn_out_kernel<<<(n1 * 3 + 255) / 256, 256, 0, stream>>>(
        Y1, SUMS(7), G(7), B(7), n1, 1.f / n1, (float*)d_out);

#undef G
#undef B
#undef SUMS
#undef GRID
}

// Round 6
// 517.539 us; speedup vs baseline: 1.4536x; 1.2405x over previous
//
#include <hip/hip_runtime.h>

typedef _Float16 HALF;
typedef _Float16 f16x8 __attribute__((ext_vector_type(8)));
typedef float f32x4 __attribute__((ext_vector_type(4)));
typedef int i32x4 __attribute__((ext_vector_type(4)));

// ---- fused weight conversion: fp32 (27*CI, CO) -> fp16 tiled [KP/32][CO_PAD][32], zero padded
struct WArgs { const float* W[8]; HALF* dst[8]; };

__global__ void convert_all_w_kernel(WArgs a)
{
    const int CIs[8]  = {64, 64, 64, 64, 32, 32, 16, 16};
    const int COs[8]  = {64, 64, 64, 32, 32, 16, 16, 3};
    const int COPs[8] = {64, 64, 64, 32, 32, 16, 16, 16};
    const int L = blockIdx.y;
    const int CI = CIs[L], CO = COs[L], COP = COPs[L];
    const int K = 27 * CI, KP = (K + 31) & ~31;
    const int total = COP * KP;
    for (int i = blockIdx.x * 256 + threadIdx.x; i < total; i += gridDim.x * 256) {
        int jp = i / KP;          // out channel (padded)
        int kp = i - jp * KP;     // k (padded)
        float v = (jp < CO && kp < K) ? a.W[L][(size_t)kp * CO + jp] : 0.f;
        a.dst[L][((size_t)(kp >> 5) * COP + jp) * 32 + (kp & 31)] = (HALF)v;
    }
}

__global__ void convert_x_kernel(const float* __restrict__ x, HALF* __restrict__ xh, int total)
{
    int i = blockIdx.x * 256 + threadIdx.x;
    if (i < total) xh[i] = (HALF)x[i];
}

// ---- bn_prep: fold the 8-way striped sum/sumsq into per-channel scale/bias ONCE
// per layer (was 256 VMEM loads per conv thread in round 5 -> VGPR 76 -> occ cliff).
__global__ void bn_prep_kernel(const float* __restrict__ sums, const float* __restrict__ g,
                               const float* __restrict__ b, float invn, int CO, int COP,
                               float* __restrict__ scbi)
{
    const int c = threadIdx.x;
    if (c >= CO) return;
    float s = 0.f, q = 0.f;
#pragma unroll
    for (int k = 0; k < 8; ++k) { s += sums[k * 128 + c]; q += sums[k * 128 + COP + c]; }
    const float mu  = s * invn;
    const float var = q * invn - mu * mu;
    const float sc  = rsqrtf(var + 1e-3f) * g[c];
    scbi[c]       = sc;
    scbi[128 + c] = b[c] - mu * sc;
}

// ---- conv: k-split across waves (round 5 structure, repaired).
// All 4 waves share the SAME 32 rows; each wave does 1/4 of the kc steps with the
// proven round-2 per-wave body (compiler 2-deep pipeline, VGPR<=64); partials
// tree-reduced via LDS. Grid = n/32 (~12 blocks/CU); with VGPR<=64 the HW allows
// 8 blocks/CU = ~29 waves/CU vs round 2's 11 -> ~2.6x in-flight gathers (Little's
// law; kernel is latency-bound: VALU 29%, MFMA 10%, HBM 5%, L2-BW ~19%).
// BN constants read precomputed from bn_prep (2x8 consecutive fp32 loads).
// sums striped 8-way by block to keep atomic chains short.
// XCD-swizzled blockIdx: contiguous row ranges share an XCD L2.
template<int CI, int CO_PAD, int NMT, bool FUSED>
__global__ __launch_bounds__(256, 2) void conv_kernel(
    const HALF* __restrict__ h, const int* __restrict__ nbr,
    const HALF* __restrict__ Wt, HALF* __restrict__ yout,
    float* __restrict__ sums, int n,
    const float* __restrict__ pscbi)
{
    constexpr int K    = 27 * CI;
    constexpr int KP   = (K + 31) & ~31;
    constexpr int NCH  = KP / 32;
    constexpr int NJB  = CO_PAD / 16;
    constexpr int NW   = 4;
    constexpr int CHK  = (NCH + NW - 1) / NW;     // kc steps per wave: 14 / 7 / 4
    constexpr int NCB  = (CI >= 64) ? 2 : 1;
    static_assert(NCB == 1 || (CHK & 1) == 0, "sc8 parity must stay compile-time");
    constexpr int LOG2CI = (CI == 64) ? 6 : ((CI == 32) ? 5 : 4);
    constexpr int ROWS  = 16 * NMT;               // 32 rows per block
    constexpr int PAIRS = NMT * NJB;

    __shared__ f32x4 lred[2][PAIRS * 64];         // 16KB for CI=64/CO=64

    const int wv   = threadIdx.x >> 6;
    const int lane = threadIdx.x & 63;
    const int l15  = lane & 15;
    const int lq   = lane >> 4;

    // bijective XCD swizzle (8 XCDs): contiguous block chunks land on one XCD
    int bid = blockIdx.x;
    {
        const int nwg = gridDim.x;
        const int q = nwg >> 3, r = nwg & 7;
        const int xcd = bid & 7, idx = bid >> 3;
        bid = (xcd < r ? xcd * (q + 1) : r * (q + 1) + (xcd - r) * q) + idx;
    }
    const int rowBase = bid * ROWS;               // same rows for all 4 waves

    f32x4 acc[NMT][NJB];
#pragma unroll
    for (int mt = 0; mt < NMT; ++mt)
#pragma unroll
        for (int jb = 0; jb < NJB; ++jb)
#pragma unroll
            for (int r = 0; r < 4; ++r) acc[mt][jb][r] = 0.f;

    int  nbo[NMT];
    bool rok[NMT];
#pragma unroll
    for (int mt = 0; mt < NMT; ++mt) {
        const int row = rowBase + mt * 16 + l15;
        rok[mt] = row < n;
        nbo[mt] = min(row, n - 1) * 27;
    }

    // per-lane normalization constants: precomputed by bn_prep, consecutive loads
    f16x8 sc8[NCB], bi8[NCB];
    if constexpr (FUSED) {
#pragma unroll
        for (int cb = 0; cb < NCB; ++cb) {
            const int c0 = cb * 32 + ((lq * 8) & (CI - 1));
#pragma unroll
            for (int j = 0; j < 8; ++j) {
                sc8[cb][j] = (HALF)pscbi[c0 + j];
                bi8[cb][j] = (HALF)pscbi[128 + c0 + j];
            }
        }
    }

    #define TAPOF(kc_) ((CI == 16) ? (2 * (kc_) + (lq >> 1)) : ((CI == 64) ? ((kc_) >> 1) : (kc_)))
    #define CHOF(kc_)  ((((kc_) * 32) + lq * 8) & (CI - 1))

    const int kc0 = wv * CHK;                     // this wave's kc range

    // ---- 2-deep rolling pipeline over this wave's chunk (round-2 body)
    int   ipf[2][NMT];
    f16x8 apf[2][NMT];
#pragma unroll
    for (int p = 0; p < 2; ++p) {
        const int kc = kc0 + p;                   // always < NCH for all CI
#pragma unroll
        for (int mt = 0; mt < NMT; ++mt) {
            const int t   = TAPOF(kc);
            const int v   = nbr[nbo[mt] + (t < 27 ? t : 26)];
            const int idx = (rok[mt] && t < 27) ? v : -1;
            ipf[p][mt] = idx;
            apf[p][mt] = *(const f16x8*)(h + ((max(idx, 0) << LOG2CI) + CHOF(kc)));
        }
    }

#pragma unroll
    for (int kc2 = 0; kc2 < CHK; ++kc2) {
        const int kc = kc0 + kc2;
        if (kc >= NCH) break;                     // wave-uniform tail guard
        const int cur = kc2 & 1;                  // compile-time (kc0 even when it matters)
        const int ccb = (NCB == 2) ? (kc2 & 1) : 0;

        // B fragments for this wave's kc (L1/L2-resident tiled Wt)
        const HALF* wb = Wt + (size_t)kc * (CO_PAD * 32) + lq * 8;
        f16x8 b[NJB];
#pragma unroll
        for (int jb = 0; jb < NJB; ++jb)
            b[jb] = *(const f16x8*)(wb + (size_t)(jb * 16 + l15) * 32);

        // take current stage
        f16x8 a_use[NMT];
        int   i_use[NMT];
#pragma unroll
        for (int mt = 0; mt < NMT; ++mt) { a_use[mt] = apf[cur][mt]; i_use[mt] = ipf[cur][mt]; }

        // refill stage with kc+2
        if (kc2 + 2 < CHK && kc + 2 < NCH) {
#pragma unroll
            for (int mt = 0; mt < NMT; ++mt) {
                const int t   = TAPOF(kc + 2);
                const int v   = nbr[nbo[mt] + (t < 27 ? t : 26)];
                const int idx = (rok[mt] && t < 27) ? v : -1;
                ipf[cur][mt] = idx;
                apf[cur][mt] = *(const f16x8*)(h + ((max(idx, 0) << LOG2CI) + CHOF(kc + 2)));
            }
        }

        // consume
#pragma unroll
        for (int mt = 0; mt < NMT; ++mt) {
            f16x8 a = a_use[mt];
            if constexpr (FUSED) {
                a = a * sc8[ccb] + bi8[ccb];      // v_pk_fma_f16
#pragma unroll
                for (int j = 0; j < 8; ++j)
                    a[j] = (a[j] < (HALF)0.f) ? (HALF)0.f : a[j];
            }
            // zero invalid lanes AFTER bn so invalid -> exact 0
            const int m = ~(i_use[mt] >> 31);
            i32x4 ai = __builtin_bit_cast(i32x4, a);
            ai.x &= m; ai.y &= m; ai.z &= m; ai.w &= m;
            a = __builtin_bit_cast(f16x8, ai);
#pragma unroll
            for (int jb = 0; jb < NJB; ++jb)
                acc[mt][jb] = __builtin_amdgcn_mfma_f32_16x16x32_f16(a, b[jb], acc[mt][jb], 0, 0, 0);
        }
    }
    #undef TAPOF
    #undef CHOF

    // ---- cross-wave tree reduction of partial accumulators (3 syncs)
    if (wv & 1) {                                 // w1 -> region0, w3 -> region1
#pragma unroll
        for (int mt = 0; mt < NMT; ++mt)
#pragma unroll
            for (int jb = 0; jb < NJB; ++jb)
                lred[wv >> 1][(mt * NJB + jb) * 64 + lane] = acc[mt][jb];
    }
    __syncthreads();
    if (!(wv & 1)) {                              // w0 += region0, w2 += region1
#pragma unroll
        for (int mt = 0; mt < NMT; ++mt)
#pragma unroll
            for (int jb = 0; jb < NJB; ++jb)
                acc[mt][jb] += lred[wv >> 1][(mt * NJB + jb) * 64 + lane];
    }
    __syncthreads();                              // region0 reads done before rewrite
    if (wv == 2) {
#pragma unroll
        for (int mt = 0; mt < NMT; ++mt)
#pragma unroll
            for (int jb = 0; jb < NJB; ++jb)
                lred[0][(mt * NJB + jb) * 64 + lane] = acc[mt][jb];
    }
    __syncthreads();

    if (wv == 0) {
#pragma unroll
        for (int mt = 0; mt < NMT; ++mt)
#pragma unroll
            for (int jb = 0; jb < NJB; ++jb)
                acc[mt][jb] += lred[0][(mt * NJB + jb) * 64 + lane];

        // epilogue: store RAW pre-norm y (fp16) + per-channel sum/sumsq (8-way striped)
        float* sl = sums + (bid & 7) * 128;
#pragma unroll
        for (int jb = 0; jb < NJB; ++jb) {
            const int col = jb * 16 + l15;
            float s = 0.f, sq = 0.f;
#pragma unroll
            for (int mt = 0; mt < NMT; ++mt) {
                const int rb = rowBase + mt * 16 + lq * 4;
#pragma unroll
                for (int r = 0; r < 4; ++r) {
                    if (rb + r < n) {
                        const float v = acc[mt][jb][r];
                        yout[(size_t)(rb + r) * CO_PAD + col] = (HALF)v;
                        s += v;
                        sq += v * v;
                    }
                }
            }
            s  += __shfl_xor(s, 16);  s  += __shfl_xor(s, 32);
            sq += __shfl_xor(sq, 16); sq += __shfl_xor(sq, 32);
            if (lane < 16) {
                atomicAdd(&sl[col], s);
                atomicAdd(&sl[CO_PAD + col], sq);
            }
        }
    }
}

// ---- final: normalize (no relu), co=3 out of CO_PAD=16, fp32 output; striped sums
__global__ void bn_out_kernel(const HALF* __restrict__ y, const float* __restrict__ sums,
                              const float* __restrict__ g, const float* __restrict__ b,
                              int n, float invn, float* __restrict__ out)
{
    int i = blockIdx.x * 256 + threadIdx.x;
    if (i >= n * 3) return;
    int row = i / 3;
    int c = i - row * 3;
    float ssum = 0.f, qsum = 0.f;
#pragma unroll
    for (int k2 = 0; k2 < 8; ++k2) {
        ssum += sums[k2 * 128 + c];
        qsum += sums[k2 * 128 + 16 + c];
    }
    float mu  = ssum * invn;
    float var = qsum * invn - mu * mu;
    float sc  = rsqrtf(var + 1e-3f) * g[c];
    out[i] = ((float)y[(size_t)row * 16 + c] - mu) * sc + b[c];
}

extern "C" void kernel_launch(void* const* d_in, const int* in_sizes, int n_in,
                              void* d_out, int out_size, void* d_ws, size_t ws_size,
                              hipStream_t stream)
{
    const int* nbr4  = (const int*)d_in[0];
    const int* inv43 = (const int*)d_in[1];
    const int* nbr3  = (const int*)d_in[2];
    const int* inv32 = (const int*)d_in[3];
    const int* nbr2  = (const int*)d_in[4];
    const int* inv21 = (const int*)d_in[5];
    const int* nbr1  = (const int*)d_in[6];
    const float* x   = (const float*)d_in[7];

    const int n4 = in_sizes[0] / 27;
    const int n3 = in_sizes[1] / 27;
    const int n2 = in_sizes[3] / 27;
    const int n1 = in_sizes[5] / 27;

    // specs: m4,i4,m3,i3,m2,i2,m1,c5
    const int CIs[8]  = {64, 64, 64, 64, 32, 32, 16, 16};
    const int COs[8]  = {64, 64, 64, 32, 32, 16, 16, 3};
    const int COPs[8] = {64, 64, 64, 32, 32, 16, 16, 16};
    int KPs[8], wtoff[8];
    int wtot = 0;
    for (int s = 0; s < 8; ++s) {
        KPs[s] = ((27 * CIs[s] + 31) / 32) * 32;
        wtoff[s] = wtot;
        wtot += COPs[s] * KPs[s];
    }

    char* ws = (char*)d_ws;
    HALF* wt = (HALF*)ws;
    size_t off = ((size_t)wtot * sizeof(HALF) + 255) & ~(size_t)255;
    float* sums = (float*)(ws + off);
    off += 8 * 1024 * sizeof(float);              // 8 layers x 8 slots x 128 floats
    off = (off + 255) & ~(size_t)255;
    float* scbi = (float*)(ws + off);
    off += 8 * 256 * sizeof(float);               // 8 layers x {scale[128], bias[128]}
    off = (off + 255) & ~(size_t)255;
    HALF* xh = (HALF*)(ws + off);
    off += ((size_t)n4 * 64 * sizeof(HALF) + 255) & ~(size_t)255;
    size_t bufElems = 0;
    {
        size_t cand[4] = {(size_t)n4 * 64, (size_t)n3 * 64, (size_t)n2 * 32, (size_t)n1 * 16};
        for (int i = 0; i < 4; ++i) if (cand[i] > bufElems) bufElems = cand[i];
    }
    HALF* Y0 = (HALF*)(ws + off);
    off += (bufElems * sizeof(HALF) + 255) & ~(size_t)255;
    HALF* Y1 = (HALF*)(ws + off);

    hipMemsetAsync(sums, 0, 8 * 1024 * sizeof(float), stream);

    WArgs wa;
    for (int s = 0; s < 8; ++s) { wa.W[s] = (const float*)d_in[8 + 3 * s]; wa.dst[s] = wt + wtoff[s]; }
    {
        int maxTotal = 64 * KPs[0];
        dim3 grid((maxTotal + 255) / 256, 8);
        convert_all_w_kernel<<<grid, 256, 0, stream>>>(wa);
    }
    convert_x_kernel<<<(n4 * 64 + 255) / 256, 256, 0, stream>>>(x, xh, n4 * 64);

#define G(s) ((const float*)d_in[9 + 3 * (s)])
#define B(s) ((const float*)d_in[10 + 3 * (s)])
#define SUMS(s) (sums + (s) * 1024)
#define SCBI(s) (scbi + (s) * 256)
#define GRID(nn) (((nn) + 31) / 32)
#define PREP(s, invn) bn_prep_kernel<<<1, 128, 0, stream>>>(SUMS(s), G(s), B(s), (invn), COs[s], COPs[s], SCBI(s))

    // m4: xh(n4,64) -> Y0 (raw)
    conv_kernel<64, 64, 2, false><<<GRID(n4), 256, 0, stream>>>(
        xh, nbr4, wt + wtoff[0], Y0, SUMS(0), n4, nullptr);
    PREP(0, 1.f / n4);
    // i4: norm(m4) fused; Y0(n4) -> Y1(n3)
    conv_kernel<64, 64, 2, true><<<GRID(n3), 256, 0, stream>>>(
        Y0, inv43, wt + wtoff[1], Y1, SUMS(1), n3, SCBI(0));
    PREP(1, 1.f / n3);
    // m3: norm(i4) fused; Y1 -> Y0
    conv_kernel<64, 64, 2, true><<<GRID(n3), 256, 0, stream>>>(
        Y1, nbr3, wt + wtoff[2], Y0, SUMS(2), n3, SCBI(1));
    PREP(2, 1.f / n3);
    // i3: norm(m3) fused; Y0(n3) -> Y1(n2), co 32
    conv_kernel<64, 32, 2, true><<<GRID(n2), 256, 0, stream>>>(
        Y0, inv32, wt + wtoff[3], Y1, SUMS(3), n2, SCBI(2));
    PREP(3, 1.f / n2);
    // m2: norm(i3) fused; Y1 -> Y0
    conv_kernel<32, 32, 2, true><<<GRID(n2), 256, 0, stream>>>(
        Y1, nbr2, wt + wtoff[4], Y0, SUMS(4), n2, SCBI(3));
    PREP(4, 1.f / n2);
    // i2: norm(m2) fused; Y0(n2) -> Y1(n1), co 16
    conv_kernel<32, 16, 2, true><<<GRID(n1), 256, 0, stream>>>(
        Y0, inv21, wt + wtoff[5], Y1, SUMS(5), n1, SCBI(4));
    PREP(5, 1.f / n1);
    // m1: norm(i2) fused; Y1 -> Y0
    conv_kernel<16, 16, 2, true><<<GRID(n1), 256, 0, stream>>>(
        Y1, nbr1, wt + wtoff[6], Y0, SUMS(6), n1, SCBI(5));
    PREP(6, 1.f / n1);
    // c5: norm(m1) fused; Y0 -> Y1 (raw), then fp32 out
    conv_kernel<16, 16, 2, true><<<GRID(n1), 256, 0, stream>>>(
        Y0, nbr1, wt + wtoff[7], Y1, SUMS(7), n1, SCBI(6));
    bn_out_kernel<<<(n1 * 3 + 255) / 256, 256, 0, stream>>>(
        Y1, SUMS(7), G(7), B(7), n1, 1.f / n1, (float*)d_out);

#undef G
#undef B
#undef SUMS
#undef SCBI
#undef GRID
#undef PREP
}